// Round 2
// baseline (1326.713 us; speedup 1.0000x reference)
//
#include <hip/hip_runtime.h>

// Problem constants (B=8192, N=8, H=256)
#define BB 8192
#define HH 256
#define HO 128            // H/2
#define NODES 24          // 3N
#define EPER 90           // 6*(N-1) + 6*N
// Output layout (float32 elements, concatenated in return order)
#define NF_SIZE (BB * NODES * HH)          // 150994944
#define EI_OFF  NF_SIZE
#define EI_SIZE (2 * BB * EPER)
#define EA_OFF  (EI_OFF + EI_SIZE)
#define BV_OFF  (EA_OFF + BB * EPER * 16)

#define NCH  8            // k-chunks
#define CF4  8            // float4 per row per chunk (32 floats)
#define WROW 9            // float4 stride per row in w_lds (8 + 1 pad -> conflict-free)

__global__ __launch_bounds__(256) void htdg_kernel(
    const float* __restrict__ zt, const float* __restrict__ za,
    const float* __restrict__ zf,
    const float* __restrict__ Wq, const float* __restrict__ bq,
    const float* __restrict__ Wk, const float* __restrict__ bk,
    const float* __restrict__ emb, float* __restrict__ out)
{
    __shared__ float  xs[NODES * HH];        // 24 KB, broadcast-read only
    __shared__ float4 wq_lds[HO * WROW];     // 18.4 KB (one k-chunk of Wq, padded)
    __shared__ float4 wk_lds[HO * WROW];     // 18.4 KB
    __shared__ float  uv[32 * HO];           // 16 KB
    __shared__ float  nrm_part[32 * 8];
    __shared__ float  dot_part[24 * 8];
    __shared__ float  rnorm_s[32];
    __shared__ float  disc_s[24];
    __shared__ int    et_s[24];
    __shared__ float  emb_s[40];

    const int b   = blockIdx.x;
    const int tid = threadIdx.x;

    // ---- Phase 0: stage nodes -> LDS, write node_feats (pure copy) ----
    {
        float4* xs4 = (float4*)xs;
        float4* nf  = (float4*)out + (size_t)b * 1536;
        #pragma unroll
        for (int it = 0; it < 6; ++it) {
            int j = tid + it * 256;          // 0..1535 float4s of this sample
            int m = j >> 9;
            int w = j & 511;
            const float4* sp = (m == 0 ? (const float4*)zt
                               : m == 1 ? (const float4*)za
                                        : (const float4*)zf) + (size_t)b * 512 + w;
            float4 v = *sp;
            xs4[j] = v;
            nf[j]  = v;
        }
        if (tid < 40) emb_s[tid] = emb[tid];
    }

    // ---- edge_index (180) + batch_vec (24), no LDS dependency ----
    {
        int j = tid;
        if (j < 180) {
            int d = (j >= 90) ? 1 : 0;
            int e = j - d * 90;
            int s, dd;
            if (e < 42) {
                int m = e / 14;
                int r = e - m * 14;
                int i = r >> 1;
                int u = m * 8 + i;
                if (r & 1) { s = u + 1; dd = u; } else { s = u; dd = u + 1; }
            } else {
                int p  = (e - 42) >> 1;
                int pr = p >> 3;
                int i  = p & 7;
                int a  = (pr == 2 ? 8 : 0) + i;
                int bb = (pr == 0 ? 8 : 16) + i;
                if (e & 1) { s = bb; dd = a; } else { s = a; dd = bb; }
            }
            int val = ((d == 0) ? s : dd) + b * 24;
            out[(size_t)EI_OFF + (size_t)d * (BB * EPER) + (size_t)b * EPER + e] = (float)val;
        }
        if (tid < 24) out[(size_t)BV_OFF + (size_t)b * 24 + tid] = (float)b;
    }

    // ---- Phase 1: matvec with LDS-staged, k-chunked weights ----
    // waves 0,1: u=Wq*x nodes 0..15 ; waves 2,3: v=Wk*x nodes 8..23
    const int wave = tid >> 6;
    const int lane = tid & 63;
    int nodeBase, slotBase;
    const float* bias;
    if (wave < 2) { bias = bq; nodeBase = wave * 8;            slotBase = wave * 8; }
    else          { bias = bk; nodeBase = (wave - 2) * 8 + 8;  slotBase = wave * 8; }

    const float4* Wq4 = (const float4*)Wq;   // row stride 64 float4
    const float4* Wk4 = (const float4*)Wk;
    // staging assignment: thread does 4 float4 per matrix per chunk
    const int srow = tid >> 3;               // rows tid>>3 + {0,32,64,96}
    const int sf4  = tid & 7;

    float acc0[8] = {0,0,0,0,0,0,0,0};
    float acc1[8] = {0,0,0,0,0,0,0,0};

    float4 rq[4], rk[4];
    // prologue: load chunk 0 into regs (coalesced: 8 lanes cover 128 B per row)
    #pragma unroll
    for (int it = 0; it < 4; ++it) {
        int row = srow + it * 32;
        rq[it] = Wq4[(size_t)row * 64 + sf4];
        rk[it] = Wk4[(size_t)row * 64 + sf4];
    }

    const float4* xb = (const float4*)xs + nodeBase * 64;
    const float4* wme = (wave < 2) ? wq_lds : wk_lds;
    const float4* wr0 = wme + (size_t)lane * WROW;
    const float4* wr1 = wme + (size_t)(lane + 64) * WROW;

    for (int c = 0; c < NCH; ++c) {
        __syncthreads();   // previous chunk's w_lds reads done (also covers xs at c=0)
        #pragma unroll
        for (int it = 0; it < 4; ++it) {
            int row = srow + it * 32;
            wq_lds[row * WROW + sf4] = rq[it];
            wk_lds[row * WROW + sf4] = rk[it];
        }
        __syncthreads();
        if (c + 1 < NCH) {   // prefetch next chunk (hides L2 latency under compute)
            #pragma unroll
            for (int it = 0; it < 4; ++it) {
                int row = srow + it * 32;
                rq[it] = Wq4[(size_t)row * 64 + (c + 1) * CF4 + sf4];
                rk[it] = Wk4[(size_t)row * 64 + (c + 1) * CF4 + sf4];
            }
        }
        const float4* xc = xb + c * CF4;
        #pragma unroll
        for (int kk = 0; kk < CF4; ++kk) {
            float4 w0 = wr0[kk];
            float4 w1 = wr1[kk];
            #pragma unroll
            for (int n = 0; n < 8; ++n) {
                float4 xv = xc[n * 64 + kk];   // broadcast (same addr all lanes)
                acc0[n] += w0.x * xv.x + w0.y * xv.y + w0.z * xv.z + w0.w * xv.w;
                acc1[n] += w1.x * xv.x + w1.y * xv.y + w1.z * xv.z + w1.w * xv.w;
            }
        }
    }
    {
        float b0 = bias[lane], b1 = bias[lane + 64];
        #pragma unroll
        for (int n = 0; n < 8; ++n) {
            uv[(slotBase + n) * HO + lane]      = acc0[n] + b0;
            uv[(slotBase + n) * HO + 64 + lane] = acc1[n] + b1;
        }
    }
    __syncthreads();

    // ---- Phase 2: norms and pair-dots ----
    {
        int slot = tid >> 3, part = tid & 7;
        const float* u = &uv[slot * HO + part * 16];
        float s = 0.f;
        #pragma unroll
        for (int o = 0; o < 16; ++o) { float v = u[o]; s += v * v; }
        nrm_part[tid] = s;
    }
    if (tid < 192) {
        int p = tid >> 3, part = tid & 7;
        int pr = p >> 3, i = p & 7;
        int aslot = (pr == 2 ? 8 : 0) + i;
        int bslot = (pr == 0 ? 16 : 24) + i;
        const float* ua = &uv[aslot * HO + part * 16];
        const float* vb = &uv[bslot * HO + part * 16];
        float s = 0.f;
        #pragma unroll
        for (int o = 0; o < 16; ++o) s += ua[o] * vb[o];
        dot_part[tid] = s;
    }
    __syncthreads();
    if (tid < 32) {
        float s = 0.f;
        #pragma unroll
        for (int j = 0; j < 8; ++j) s += nrm_part[tid * 8 + j];
        rnorm_s[tid] = 1.0f / fmaxf(sqrtf(s), 1e-12f);
    }
    __syncthreads();
    if (tid < 24) {
        float s = 0.f;
        #pragma unroll
        for (int j = 0; j < 8; ++j) s += dot_part[tid * 8 + j];
        int pr = tid >> 3, i = tid & 7;
        int aslot = (pr == 2 ? 8 : 0) + i;
        int bslot = (pr == 0 ? 16 : 24) + i;
        float t   = s * rnorm_s[aslot] * rnorm_s[bslot];
        float dsc = 1.0f / (1.0f + expf(t));   // 1 - sigmoid(t)
        disc_s[tid] = dsc;
        et_s[tid]   = (dsc > 0.4f) ? 4 : 3;
    }
    __syncthreads();

    // ---- Phase 3: edge_attr (90 rows x 16 floats) ----
    {
        float* ea = out + (size_t)EA_OFF + (size_t)b * (EPER * 16);
        #pragma unroll
        for (int it = 0; it < 6; ++it) {
            int j = tid + it * 256;
            if (j < 1440) {
                int row = j >> 4, c = j & 15;
                float val;
                if (row < 42) {
                    int m = row / 14;
                    if      (c < 8)   val = emb_s[m * 8 + c];
                    else if (c == 9)  val = 0.125f;
                    else if (c == 10) val = 1.0f;
                    else if (c == 11) val = (float)m * 0.25f;
                    else              val = 0.0f;
                } else {
                    int p  = (row - 42) >> 1;
                    int et = et_s[p];
                    if      (c < 8)   val = emb_s[et * 8 + c];
                    else if (c == 8)  val = disc_s[p];
                    else if (c == 11) val = (float)et * 0.25f;
                    else              val = 0.0f;
                }
                ea[j] = val;
            }
        }
    }
}

extern "C" void kernel_launch(void* const* d_in, const int* in_sizes, int n_in,
                              void* d_out, int out_size, void* d_ws, size_t ws_size,
                              hipStream_t stream) {
    const float* zt  = (const float*)d_in[0];
    const float* za  = (const float*)d_in[1];
    const float* zf  = (const float*)d_in[2];
    const float* Wq  = (const float*)d_in[3];
    const float* bq  = (const float*)d_in[4];
    const float* Wk  = (const float*)d_in[5];
    const float* bk  = (const float*)d_in[6];
    const float* emb = (const float*)d_in[7];
    htdg_kernel<<<BB, 256, 0, stream>>>(zt, za, zf, Wq, bq, Wk, bk, emb, (float*)d_out);
}